// Round 5
// baseline (179.645 us; speedup 1.0000x reference)
//
#include <hip/hip_runtime.h>

// AdderNet 2D: out[n,f,i,j] = -sum_{c,ki,kj} |W[f,c,ki,kj] - xpad[n,c,i+ki,j+kj]|
// x: [8,64,32,32] f32, W: [64,64,3,3] f32, out: [8,64,32,32] f32
//
// R5: NO split-C, NO atomics, NO workspace. R2-R4 proved every split-C
// combine pays 9-75x write amplification vs the 2 MB true output. Instead:
// block = (n, single filter f, half-plane of 16 rows), T=128, 4 px/thread
// (2x2). The 9 weights per channel are block-uniform -> s_load/SGPR operands
// (zero DS cost), which is what lets 4 px/thread stay DS-balanced:
// per cc: DS = 4 fused ds_read2_b64 (~48 cyc) vs VALU 72 instr (N/2=36).
// 1024 blocks x 2 waves = 2048 waves = 2/SIMD. Epilogue: LDS transpose ->
// one coalesced float4 store per thread.

#define CCHUNK  8
#define XSTRIDE 36                 // LDS row stride (floats): even -> 8B-aligned pairs
#define XROWS   18                 // 16 rows + halo
#define XCH     (XROWS * XSTRIDE)  // 648 floats per channel

__global__ __launch_bounds__(128, 2)
void adder2d_kernel(const float* __restrict__ x,
                    const float* __restrict__ Wt,
                    float* __restrict__ out) {
    __shared__ __align__(16) float xs[CCHUNK * XCH];   // 20736 B

    const int bid  = blockIdx.x;
    const int f    = bid & 63;          // filter fastest: 128 blocks share x[n]
    const int half = (bid >> 6) & 1;
    const int n    = bid >> 7;
    const int i0   = half * 16;
    const int tid  = threadIdx.x;
    const int tx   = tid & 15;          // out cols 2tx, 2tx+1
    const int ty   = tid >> 4;          // out rows i0+2ty, i0+2ty+1

    float acc00 = 0.f, acc01 = 0.f, acc10 = 0.f, acc11 = 0.f;

    const float* xn = x + (size_t)n * 64 * 1024;
    const float* wf = Wt + (size_t)f * 576;

    for (int c0 = 0; c0 < 64; c0 += CCHUNK) {
        // ---- stage x chunk: LDS row = global_row - (i0-1), col idx = img_col + 1
        for (int idx = tid; idx < CCHUNK * XCH; idx += 128) {
            const int cc  = idx / XCH;
            const int rem = idx - cc * XCH;
            const int row = rem / XSTRIDE;
            const int col = rem - row * XSTRIDE;
            const int ir  = i0 + row - 1;
            const int ic  = col - 1;
            float v = 0.0f;
            if ((unsigned)ir < 32u && (unsigned)ic < 32u)
                v = xn[(size_t)(c0 + cc) * 1024 + ir * 32 + ic];
            xs[idx] = v;
        }
        __syncthreads();

#pragma unroll
        for (int cc = 0; cc < CCHUNK; ++cc) {
            // 9 block-uniform weights -> s_load / SGPR operands
            const float* wp = wf + (size_t)(c0 + cc) * 9;
            const float w0 = wp[0], w1 = wp[1], w2 = wp[2];
            const float w3 = wp[3], w4 = wp[4], w5 = wp[5];
            const float w6 = wp[6], w7 = wp[7], w8 = wp[8];

            // x window: LDS rows 2ty..2ty+3, col idx 2tx..2tx+3 (8B-aligned pairs)
            const float* p = &xs[cc * XCH + 2 * ty * XSTRIDE + 2 * tx];
            float xw[4][4];
#pragma unroll
            for (int r4 = 0; r4 < 4; ++r4) {
                const float2 a = *(const float2*)(p + r4 * XSTRIDE);
                const float2 b = *(const float2*)(p + r4 * XSTRIDE + 2);
                xw[r4][0] = a.x; xw[r4][1] = a.y;
                xw[r4][2] = b.x; xw[r4][3] = b.y;
            }
            const float w[9] = {w0, w1, w2, w3, w4, w5, w6, w7, w8};
#pragma unroll
            for (int ki = 0; ki < 3; ++ki)
#pragma unroll
                for (int kj = 0; kj < 3; ++kj) {
                    const float wv = w[ki * 3 + kj];
                    acc00 += fabsf(wv - xw[ki + 0][kj + 0]);
                    acc01 += fabsf(wv - xw[ki + 0][kj + 1]);
                    acc10 += fabsf(wv - xw[ki + 1][kj + 0]);
                    acc11 += fabsf(wv - xw[ki + 1][kj + 1]);
                }
        }
        __syncthreads();
    }

    // ---- epilogue: LDS transpose -> coalesced float4 stores (no atomics)
    xs[(2 * ty + 0) * 32 + 2 * tx + 0] = -acc00;
    xs[(2 * ty + 0) * 32 + 2 * tx + 1] = -acc01;
    xs[(2 * ty + 1) * 32 + 2 * tx + 0] = -acc10;
    xs[(2 * ty + 1) * 32 + 2 * tx + 1] = -acc11;
    __syncthreads();
    float4* dst = (float4*)(out + ((size_t)(n * 64 + f) * 1024 + half * 512));
    dst[tid] = *(const float4*)&xs[tid * 4];
}

extern "C" void kernel_launch(void* const* d_in, const int* in_sizes, int n_in,
                              void* d_out, int out_size, void* d_ws, size_t ws_size,
                              hipStream_t stream) {
    const float* x  = (const float*)d_in[0];
    const float* W  = (const float*)d_in[1];
    float* out      = (float*)d_out;
    hipLaunchKernelGGL(adder2d_kernel, dim3(1024), dim3(128), 0, stream,
                       x, W, out);
}

// Round 6
// 79.451 us; speedup vs baseline: 2.2611x; 2.2611x over previous
//
#include <hip/hip_runtime.h>
#include <stdint.h>

// AdderNet 2D: out[n,f,i,j] = -sum_{c,ki,kj} |W[f,c,ki,kj] - xpad[n,c,i+ki,j+kj]|
// x: [8,64,32,32] f32, W: [64,64,3,3] f32, out: [8,64,32,32] f32
//
// R6: |w-x| = (w+x) - 2*min(w,x)  =>  out = 2*Sum(min) - SW_f - Sx_window.
// fp16 channel-paired: per 2 terms = v_pk_min_f16 (w broadcast from SGPR,
// prepacked pairs in d_ws) + v_dot2_f32_f16 with (1,1) -> 1 instr/term,
// fp32 accumulation. Block 512T = 8 waves; each wave one 8-channel slice of
// the same (n, 4 filters, 16x16 quarter plane); LDS combine (no global
// partials/atomics). Grid 512 -> 16 waves/CU.

typedef _Float16 half2v __attribute__((ext_vector_type(2)));

#define XS   20                 // u32 stride per LDS row
#define RH   18                 // rows incl. halo
#define CH2  32                 // channel pairs
#define XCHW (RH * XS)          // 360 u32 per channel-pair
#define W2_ELEMS (CH2 * 16 * 4 * 9)     // 18432 u32
#define WS_NEEDED (W2_ELEMS * 4 + 64 * 4)

// ---------- pre-kernel: pack W into fp16 channel-pairs + per-filter sums ----
__global__ __launch_bounds__(64)
void prep_kernel(const float* __restrict__ W, uint32_t* __restrict__ W2,
                 float* __restrict__ SW) {
    const int f    = blockIdx.x;     // 0..63
    const int lane = threadIdx.x;    // 0..63
    float s = 0.0f;
    for (int i = lane; i < CH2 * 9; i += 64) {
        const int ch2 = i / 9;
        const int k   = i - ch2 * 9;
        const float a = W[(size_t)f * 576 + (2 * ch2) * 9 + k];
        const float b = W[(size_t)f * 576 + (2 * ch2 + 1) * 9 + k];
        const _Float16 ha = (_Float16)a;   // RNE
        const _Float16 hb = (_Float16)b;
        uint16_t ua = __builtin_bit_cast(uint16_t, ha);
        uint16_t ub = __builtin_bit_cast(uint16_t, hb);
        // layout: W2[((ch2*16 + fg)*4 + fsub)*9 + k], f = fg*4+fsub
        W2[((size_t)ch2 * 16 + (f >> 2)) * 36 + (f & 3) * 9 + k] =
            (uint32_t)ua | ((uint32_t)ub << 16);
        s += (float)ha + (float)hb;
    }
#pragma unroll
    for (int m = 32; m >= 1; m >>= 1) s += __shfl_xor(s, m, 64);
    if (lane == 0) SW[f] = s;
}

// ---------------------------- main kernel ----------------------------------
__global__ __launch_bounds__(512)
void adder2d_kernel(const float* __restrict__ x,
                    const uint32_t* __restrict__ W2,
                    const float* __restrict__ SW,
                    float* __restrict__ out) {
    __shared__ uint32_t xs[CH2 * XCHW];          // 46080 B (reused for partials)

    const int bid     = blockIdx.x;
    const int quarter = bid & 3;
    const int fg      = (bid >> 2) & 15;
    const int n       = bid >> 6;
    const int r0      = (quarter >> 1) * 16;
    const int c0      = (quarter & 1) * 16;
    const int tid     = threadIdx.x;

    // ---- stage x quarter (+halo) as fp16 channel-pairs ----
    {
        const int ch2s = tid >> 4;
        const int sub  = tid & 15;
        const float* xa = x + ((size_t)n * 64 + 2 * ch2s) * 1024;
        for (int cell = sub; cell < RH * RH; cell += 16) {
            const int row = cell / RH;
            const int col = cell - row * RH;
            const int ir  = r0 + row - 1;
            const int ic  = c0 + col - 1;
            float a = 0.0f, b = 0.0f;
            if ((unsigned)ir < 32u && (unsigned)ic < 32u) {
                a = xa[ir * 32 + ic];
                b = xa[1024 + ir * 32 + ic];
            }
            const _Float16 ha = (_Float16)a;     // RNE
            const _Float16 hb = (_Float16)b;
            xs[ch2s * XCHW + row * XS + col] =
                (uint32_t)__builtin_bit_cast(uint16_t, ha) |
                ((uint32_t)__builtin_bit_cast(uint16_t, hb) << 16);
        }
    }
    __syncthreads();

    const int wave = __builtin_amdgcn_readfirstlane(tid >> 6);  // SGPR-uniform
    const int lane = tid & 63;
    const int tx   = lane & 7;        // px cols 2tx, 2tx+1
    const int ty   = lane >> 3;       // px rows 2ty, 2ty+1

    const half2v one2 = {(_Float16)1.0f, (_Float16)1.0f};
    float acc[16];                    // [f][sub]  sub = sr*2+sc
    float sx[4];
#pragma unroll
    for (int i = 0; i < 16; ++i) acc[i] = 0.0f;
#pragma unroll
    for (int i = 0; i < 4; ++i) sx[i] = 0.0f;

#pragma unroll
    for (int i = 0; i < 4; ++i) {
        const int ch2 = wave * 4 + i;
        // 36 block/wave-uniform w-pairs -> s_load
        const uint32_t* wp = W2 + ((size_t)ch2 * 16 + fg) * 36;

        // 4x4 window of channel-pairs (8B-aligned ds_read_b64 pairs)
        uint32_t xw[4][4];
#pragma unroll
        for (int r = 0; r < 4; ++r) {
            const uint32_t* p = &xs[ch2 * XCHW + (2 * ty + r) * XS + 2 * tx];
            const uint2 A = *(const uint2*)p;
            const uint2 B = *(const uint2*)(p + 2);
            xw[r][0] = A.x; xw[r][1] = A.y; xw[r][2] = B.x; xw[r][3] = B.y;
        }

#pragma unroll
        for (int f = 0; f < 4; ++f) {
#pragma unroll
            for (int k = 0; k < 9; ++k) {
                const int ki = k / 3, kj = k - 3 * ki;
                const half2v w2 = __builtin_bit_cast(half2v, wp[f * 9 + k]);
#pragma unroll
                for (int sr = 0; sr < 2; ++sr)
#pragma unroll
                    for (int sc = 0; sc < 2; ++sc) {
                        const half2v xv =
                            __builtin_bit_cast(half2v, xw[sr + ki][sc + kj]);
                        const half2v m = __builtin_elementwise_min(w2, xv);
                        acc[f * 4 + sr * 2 + sc] = __builtin_amdgcn_fdot2(
                            m, one2, acc[f * 4 + sr * 2 + sc], false);
                    }
            }
        }
        // window x-sum (shared across filters)
#pragma unroll
        for (int k = 0; k < 9; ++k) {
            const int ki = k / 3, kj = k - 3 * ki;
#pragma unroll
            for (int sr = 0; sr < 2; ++sr)
#pragma unroll
                for (int sc = 0; sc < 2; ++sc) {
                    const half2v xv =
                        __builtin_bit_cast(half2v, xw[sr + ki][sc + kj]);
                    sx[sr * 2 + sc] = __builtin_amdgcn_fdot2(
                        xv, one2, sx[sr * 2 + sc], false);
                }
        }
    }

    // ---- combine the 8 channel-slice waves via LDS ----
    __syncthreads();                       // all xs reads done
    float* ps = (float*)xs;                // [8 waves][64 lanes][20 slots]
#pragma unroll
    for (int s = 0; s < 16; ++s) ps[((wave * 64 + lane) * 20) + s] = acc[s];
#pragma unroll
    for (int s = 0; s < 4; ++s) ps[((wave * 64 + lane) * 20) + 16 + s] = sx[s];
    __syncthreads();

    // ---- reduce + store: 2 outputs/thread (same px, 2 filters) ----
    const int px  = tid & 255;
    const int fp  = tid >> 8;              // 0..1
    const int row = px >> 4, col = px & 15;
    const int lane_s = (row >> 1) * 8 + (col >> 1);
    const int sub_s  = (row & 1) * 2 + (col & 1);

    float sxs = 0.0f;
#pragma unroll
    for (int w = 0; w < 8; ++w)
        sxs += ps[(w * 64 + lane_s) * 20 + 16 + sub_s];
#pragma unroll
    for (int f2 = 0; f2 < 2; ++f2) {
        const int f = fp * 2 + f2;
        float m = 0.0f;
#pragma unroll
        for (int w = 0; w < 8; ++w)
            m += ps[(w * 64 + lane_s) * 20 + f * 4 + sub_s];
        const float val = 2.0f * m - SW[fg * 4 + f] - sxs;
        out[(((size_t)n * 64 + fg * 4 + f) * 32 + r0 + row) * 32 + c0 + col] = val;
    }
}

// ------------------- fallback (R2 structure, fp32, proven) -----------------
#define FB_CCHUNK 16
#define FB_XROW 36
#define FB_XCH (10 * FB_XROW)
#define FB_WPAD 12
__global__ __launch_bounds__(256, 6)
void adder2d_fb(const float* __restrict__ x, const float* __restrict__ Wt,
                float* __restrict__ out) {
    __shared__ float fxs[FB_CCHUNK * FB_XCH];
    __shared__ float fws[4 * FB_CCHUNK * FB_WPAD];
    const int bid = blockIdx.x;
    const int ks = bid & 3, fg = (bid >> 2) & 15, tile = (bid >> 6) & 3, n = bid >> 8;
    const int c0 = ks * FB_CCHUNK, f0 = fg * 4, i0 = tile * 8, tid = threadIdx.x;
    for (int idx = tid; idx < 4 * FB_CCHUNK * 9; idx += 256) {
        const int f = idx / (FB_CCHUNK * 9), rem = idx - f * (FB_CCHUNK * 9);
        const int cc = rem / 9, kk = rem - cc * 9;
        fws[(f * FB_CCHUNK + cc) * FB_WPAD + kk] =
            Wt[((size_t)(f0 + f) * 64 + (c0 + cc)) * 9 + kk];
    }
    const float* xn = x + ((size_t)n * 64 + c0) * 1024;
    for (int idx = tid; idx < FB_CCHUNK * FB_XCH; idx += 256) {
        const int cc = idx / FB_XCH, rem = idx - cc * FB_XCH;
        const int row = rem / FB_XROW, col = rem - row * FB_XROW;
        const int ir = i0 + row - 1, ic = col - 1;
        float v = 0.0f;
        if ((unsigned)ir < 32u && (unsigned)ic < 32u) v = xn[cc * 1024 + ir * 32 + ic];
        fxs[idx] = v;
    }
    __syncthreads();
    const int r = tid >> 5, j = tid & 31;
    float acc[4] = {0, 0, 0, 0};
#pragma unroll 2
    for (int cc = 0; cc < FB_CCHUNK; ++cc) {
        const float* xp = &fxs[cc * FB_XCH + r * FB_XROW + j];
        const float x00 = xp[0], x01 = xp[1], x02 = xp[2];
        const float x10 = xp[36], x11 = xp[37], x12 = xp[38];
        const float x20 = xp[72], x21 = xp[73], x22 = xp[74];
#pragma unroll
        for (int f = 0; f < 4; ++f) {
            const float* wq = &fws[(f * FB_CCHUNK + cc) * FB_WPAD];
            acc[f] += fabsf(wq[0] - x00) + fabsf(wq[1] - x01) + fabsf(wq[2] - x02)
                    + fabsf(wq[3] - x10) + fabsf(wq[4] - x11) + fabsf(wq[5] - x12)
                    + fabsf(wq[6] - x20) + fabsf(wq[7] - x21) + fabsf(wq[8] - x22);
        }
    }
    const int irow = i0 + r;
#pragma unroll
    for (int f = 0; f < 4; ++f)
        atomicAdd(&out[(((size_t)n * 64 + (f0 + f)) * 32 + irow) * 32 + j], -acc[f]);
}

extern "C" void kernel_launch(void* const* d_in, const int* in_sizes, int n_in,
                              void* d_out, int out_size, void* d_ws, size_t ws_size,
                              hipStream_t stream) {
    const float* x  = (const float*)d_in[0];
    const float* W  = (const float*)d_in[1];
    float* out      = (float*)d_out;

    if (ws_size >= (size_t)WS_NEEDED) {
        uint32_t* W2 = (uint32_t*)d_ws;
        float* SW    = (float*)((char*)d_ws + W2_ELEMS * 4);
        hipLaunchKernelGGL(prep_kernel, dim3(64), dim3(64), 0, stream, W, W2, SW);
        hipLaunchKernelGGL(adder2d_kernel, dim3(512), dim3(512), 0, stream,
                           x, W2, SW, out);
    } else {
        hipMemsetAsync(d_out, 0, (size_t)out_size * sizeof(float), stream);
        hipLaunchKernelGGL(adder2d_fb, dim3(2048), dim3(256), 0, stream, x, W, out);
    }
}